// Round 1
// baseline (227.874 us; speedup 1.0000x reference)
//
#include <hip/hip_runtime.h>

#define N_NODES 4096
#define E_EDGES 131072
#define IN_F    256
#define OUT_F   64
#define HEADS   4
#define HC      256        // HEADS*OUT_F
#define HASH_T  262144     // 2^18, 2x oversized for E
#define HASH_MASK (HASH_T - 1)

__device__ __forceinline__ unsigned hash_slot(unsigned key) {
    return (key * 2654435761u) >> 14;   // top 18 bits of Knuth hash -> [0, 2^18)
}

// ---------------- K0: init scratch ----------------
__global__ void k_init(int* hashKey, int* hashVal, int* rowcnt, float* S) {
    int i = blockIdx.x * blockDim.x + threadIdx.x;
    if (i < HASH_T) { hashKey[i] = -1; hashVal[i] = -1; }
    if (i < N_NODES) rowcnt[i] = 0;
    if (i < HC)      S[i] = 0.f;
}

// ---------------- K1: Wh = h @ W^T, plus s1/s2 per node/head ----------------
// 8 nodes per block; thread t = head*64+o computes channel t for 8 nodes.
__global__ __launch_bounds__(256) void k_linear(
        const float* __restrict__ h, const float* __restrict__ W,
        const float* __restrict__ a,
        float* __restrict__ Wh, float* __restrict__ s1, float* __restrict__ s2) {
    __shared__ float hs[8][IN_F];
    const int t = threadIdx.x;
    const int node0 = blockIdx.x * 8;
    for (int n = 0; n < 8; ++n) hs[n][t] = h[(size_t)(node0 + n) * IN_F + t];
    __syncthreads();

    float acc[8] = {0.f, 0.f, 0.f, 0.f, 0.f, 0.f, 0.f, 0.f};
    const float* wrow = W + (size_t)t * IN_F;     // W[head][o][:] with t = head*64+o
    for (int in = 0; in < IN_F; ++in) {
        float wv = wrow[in];
#pragma unroll
        for (int n = 0; n < 8; ++n) acc[n] += wv * hs[n][in];
    }

    const int head = t >> 6, lane = t & 63;
    const float a1 = a[head * 2 * OUT_F + lane];
    const float a2 = a[head * 2 * OUT_F + OUT_F + lane];
    for (int n = 0; n < 8; ++n) {
        Wh[(size_t)(node0 + n) * HC + t] = acc[n];
        float p1 = acc[n] * a1;
        float p2 = acc[n] * a2;
#pragma unroll
        for (int o = 32; o > 0; o >>= 1) {
            p1 += __shfl_xor(p1, o, 64);
            p2 += __shfl_xor(p2, o, 64);
        }
        if (lane == 0) {
            s1[(node0 + n) * HEADS + head] = p1;
            s2[(node0 + n) * HEADS + head] = p2;
        }
    }
}

// ---------------- K2: S[c] = sum_j Wh[j][c] ----------------
__global__ void k_colsum(const float* __restrict__ Wh, float* S) {
    const int t = threadIdx.x;
    const int chunk = N_NODES / 32;
    const int i0 = blockIdx.x * chunk;
    float s = 0.f;
    for (int i = i0; i < i0 + chunk; ++i) s += Wh[(size_t)i * HC + t];
    atomicAdd(&S[t], s);
}

// ---------------- K3: hash insert (dedupe, last-k-wins) ----------------
__global__ void k_hash_insert(const int* __restrict__ rows, const int* __restrict__ cols,
                              int* hashKey, int* hashVal) {
    int k = blockIdx.x * blockDim.x + threadIdx.x;
    if (k >= E_EDGES) return;
    const int key = (rows[k] << 12) | cols[k];
    unsigned slot = hash_slot((unsigned)key);
    while (true) {
        int old = atomicCAS(&hashKey[slot], -1, key);
        if (old == -1 || old == key) { atomicMax(&hashVal[slot], k); break; }
        slot = (slot + 1) & HASH_MASK;
    }
}

// ---------------- K4: per-edge e values, winner flag, row counts ----------------
__global__ void k_edge(const int* __restrict__ rows, const int* __restrict__ cols,
                       const float* __restrict__ s1, const float* __restrict__ s2,
                       const int* __restrict__ hashKey, const int* __restrict__ hashVal,
                       float* __restrict__ e_vals, int* __restrict__ winner,
                       int* __restrict__ rowcnt) {
    int k = blockIdx.x * blockDim.x + threadIdx.x;
    if (k >= E_EDGES) return;
    const int r = rows[k], c = cols[k];
#pragma unroll
    for (int hh = 0; hh < HEADS; ++hh) {
        float x = s1[r * HEADS + hh] + s2[c * HEADS + hh];
        e_vals[(size_t)k * HEADS + hh] = (x > 0.f) ? x : 0.2f * x;   // leaky_relu 0.2
    }
    const int key = (r << 12) | c;
    unsigned slot = hash_slot((unsigned)key);
    while (hashKey[slot] != key) slot = (slot + 1) & HASH_MASK;
    const int win = (hashVal[slot] == k) ? 1 : 0;
    winner[k] = win;
    if (win) atomicAdd(&rowcnt[r], 1);
}

// ---------------- K5: exclusive scan of rowcnt -> rowptr, cursor ----------------
__global__ __launch_bounds__(1024) void k_scan(const int* __restrict__ rowcnt,
                                               int* rowptr, int* cursor) {
    __shared__ int part[1024];
    const int t = threadIdx.x;
    const int base = t * 4;
    int c0 = rowcnt[base], c1 = rowcnt[base + 1], c2 = rowcnt[base + 2], c3 = rowcnt[base + 3];
    int s = c0 + c1 + c2 + c3;
    part[t] = s;
    __syncthreads();
    for (int off = 1; off < 1024; off <<= 1) {
        int v = (t >= off) ? part[t - off] : 0;
        __syncthreads();
        part[t] += v;
        __syncthreads();
    }
    int excl = part[t] - s;
    rowptr[base]     = excl;
    rowptr[base + 1] = excl + c0;
    rowptr[base + 2] = excl + c0 + c1;
    rowptr[base + 3] = excl + c0 + c1 + c2;
    cursor[base]     = rowptr[base];
    cursor[base + 1] = rowptr[base + 1];
    cursor[base + 2] = rowptr[base + 2];
    cursor[base + 3] = rowptr[base + 3];
    if (t == 1023) rowptr[N_NODES] = part[1023];
}

// ---------------- K6: CSR fill with winner edge ids ----------------
__global__ void k_csr_fill(const int* __restrict__ rows, const int* __restrict__ winner,
                           int* cursor, int* edgelist) {
    int k = blockIdx.x * blockDim.x + threadIdx.x;
    if (k >= E_EDGES) return;
    if (winner[k]) {
        int pos = atomicAdd(&cursor[rows[k]], 1);
        edgelist[pos] = k;
    }
}

// ---------------- K7: per-(row,head) softmax stats ----------------
__global__ __launch_bounds__(256) void k_rowstats(
        const int* __restrict__ rowptr, const int* __restrict__ edgelist,
        const float* __restrict__ e_vals,
        float* __restrict__ m_arr, float* __restrict__ d_arr,
        float* __restrict__ b_arr, float* __restrict__ bsum) {
    const int i = blockIdx.x;
    const int t = threadIdx.x, head = t >> 6, lane = t & 63;
    const int start = rowptr[i], end = rowptr[i + 1];

    float emax = -1e30f;
    for (int p = start + lane; p < end; p += 64) {
        float v = e_vals[(size_t)edgelist[p] * HEADS + head];
        emax = fmaxf(emax, v);
    }
#pragma unroll
    for (int o = 32; o > 0; o >>= 1) emax = fmaxf(emax, __shfl_xor(emax, o, 64));
    const float m = fmaxf(emax, 0.f);   // dense row always has zero background cells

    float ssum = 0.f;
    for (int p = start + lane; p < end; p += 64) {
        float v = e_vals[(size_t)edgelist[p] * HEADS + head];
        ssum += __expf(v - m);
    }
#pragma unroll
    for (int o = 32; o > 0; o >>= 1) ssum += __shfl_xor(ssum, o, 64);

    __shared__ float bsh[HEADS];
    if (lane == 0) {
        const int cnt = end - start;
        float denom = ssum + (float)(N_NODES - cnt) * __expf(-m);
        m_arr[i * HEADS + head] = m;
        d_arr[i * HEADS + head] = denom;
        float b = __expf(-m) / denom;
        b_arr[i * HEADS + head] = b;
        bsh[head] = b;
    }
    __syncthreads();
    if (t == 0) bsum[i] = 0.25f * (bsh[0] + bsh[1] + bsh[2] + bsh[3]);
}

// ---------------- K8: dense attn fill with per-row background ----------------
__global__ __launch_bounds__(256) void k_attn_fill(const float* __restrict__ bsum,
                                                   float* __restrict__ attn) {
    const int i = blockIdx.x;
    const float v = bsum[i];
    float4 v4 = make_float4(v, v, v, v);
    float4* rowp = (float4*)(attn + (size_t)i * N_NODES);
    for (int j = threadIdx.x; j < N_NODES / 4; j += blockDim.x) rowp[j] = v4;
}

// ---------------- K9: scatter winner cells into attn ----------------
__global__ void k_attn_scatter(const int* __restrict__ rows, const int* __restrict__ cols,
                               const int* __restrict__ winner,
                               const float* __restrict__ e_vals,
                               const float* __restrict__ m_arr, const float* __restrict__ d_arr,
                               float* __restrict__ attn) {
    int k = blockIdx.x * blockDim.x + threadIdx.x;
    if (k >= E_EDGES || !winner[k]) return;
    const int r = rows[k], c = cols[k];
    float s = 0.f;
#pragma unroll
    for (int hh = 0; hh < HEADS; ++hh)
        s += __expf(e_vals[(size_t)k * HEADS + hh] - m_arr[r * HEADS + hh]) / d_arr[r * HEADS + hh];
    attn[(size_t)r * N_NODES + c] = 0.25f * s;
}

// ---------------- K10: out0 = relu(b*S + sum_edges (w-b)*Wh[col]) ----------------
__global__ __launch_bounds__(256) void k_out0(
        const int* __restrict__ rowptr, const int* __restrict__ edgelist,
        const int* __restrict__ cols, const float* __restrict__ e_vals,
        const float* __restrict__ m_arr, const float* __restrict__ d_arr,
        const float* __restrict__ b_arr, const float* __restrict__ S,
        const float* __restrict__ Wh, float* __restrict__ out0) {
    const int i = blockIdx.x, t = threadIdx.x, head = t >> 6;
    const float m  = m_arr[i * HEADS + head];
    const float dn = d_arr[i * HEADS + head];
    const float b  = b_arr[i * HEADS + head];
    float acc = b * S[t];
    const int start = rowptr[i], end = rowptr[i + 1];
    for (int p = start; p < end; ++p) {
        const int k = edgelist[p];
        const float w = __expf(e_vals[(size_t)k * HEADS + head] - m) / dn;
        acc += (w - b) * Wh[(size_t)cols[k] * HC + t];
    }
    out0[(size_t)i * HC + t] = fmaxf(acc, 0.f);
}

extern "C" void kernel_launch(void* const* d_in, const int* in_sizes, int n_in,
                              void* d_out, int out_size, void* d_ws, size_t ws_size,
                              hipStream_t stream) {
    const float* h  = (const float*)d_in[0];
    const int*   ei = (const int*)d_in[1];
    const float* W  = (const float*)d_in[2];
    const float* a  = (const float*)d_in[3];
    const int* rows = ei;
    const int* cols = ei + E_EDGES;

    float* out0 = (float*)d_out;
    float* attn = out0 + (size_t)N_NODES * HC;

    // workspace carve (all offsets 256B aligned)
    char* p = (char*)d_ws;
    auto carve = [&](size_t bytes) { char* q = p; p += (bytes + 255) & ~(size_t)255; return q; };
    float* Wh      = (float*)carve(sizeof(float) * (size_t)N_NODES * HC);
    float* s1      = (float*)carve(sizeof(float) * N_NODES * HEADS);
    float* s2      = (float*)carve(sizeof(float) * N_NODES * HEADS);
    float* S       = (float*)carve(sizeof(float) * HC);
    float* e_vals  = (float*)carve(sizeof(float) * (size_t)E_EDGES * HEADS);
    float* m_arr   = (float*)carve(sizeof(float) * N_NODES * HEADS);
    float* d_arr   = (float*)carve(sizeof(float) * N_NODES * HEADS);
    float* b_arr   = (float*)carve(sizeof(float) * N_NODES * HEADS);
    float* bsum    = (float*)carve(sizeof(float) * N_NODES);
    int* hashKey   = (int*)carve(sizeof(int) * HASH_T);
    int* hashVal   = (int*)carve(sizeof(int) * HASH_T);
    int* winner    = (int*)carve(sizeof(int) * E_EDGES);
    int* rowcnt    = (int*)carve(sizeof(int) * N_NODES);
    int* rowptr    = (int*)carve(sizeof(int) * (N_NODES + 4));
    int* cursor    = (int*)carve(sizeof(int) * N_NODES);
    int* edgelist  = (int*)carve(sizeof(int) * E_EDGES);

    k_init<<<(HASH_T + 255) / 256, 256, 0, stream>>>(hashKey, hashVal, rowcnt, S);
    k_linear<<<N_NODES / 8, 256, 0, stream>>>(h, W, a, Wh, s1, s2);
    k_colsum<<<32, 256, 0, stream>>>(Wh, S);
    k_hash_insert<<<E_EDGES / 256, 256, 0, stream>>>(rows, cols, hashKey, hashVal);
    k_edge<<<E_EDGES / 256, 256, 0, stream>>>(rows, cols, s1, s2, hashKey, hashVal,
                                              e_vals, winner, rowcnt);
    k_scan<<<1, 1024, 0, stream>>>(rowcnt, rowptr, cursor);
    k_csr_fill<<<E_EDGES / 256, 256, 0, stream>>>(rows, winner, cursor, edgelist);
    k_rowstats<<<N_NODES, 256, 0, stream>>>(rowptr, edgelist, e_vals, m_arr, d_arr, b_arr, bsum);
    k_attn_fill<<<N_NODES, 256, 0, stream>>>(bsum, attn);
    k_attn_scatter<<<E_EDGES / 256, 256, 0, stream>>>(rows, cols, winner, e_vals,
                                                      m_arr, d_arr, attn);
    k_out0<<<N_NODES, 256, 0, stream>>>(rowptr, edgelist, cols, e_vals, m_arr, d_arr,
                                        b_arr, S, Wh, out0);
}

// Round 3
// 203.573 us; speedup vs baseline: 1.1194x; 1.1194x over previous
//
#include <hip/hip_runtime.h>

#define N_NODES 4096
#define E_EDGES 131072
#define IN_F    256
#define OUT_F   64
#define HEADS   4
#define HC      256        // HEADS*OUT_F
#define HASH_T  262144     // 2^18, 2x oversized for E
#define HASH_MASK (HASH_T - 1)
#define ECAP    512        // per-row LDS edge cache (Poisson(32) tail << 512)

typedef float v4f __attribute__((ext_vector_type(4)));   // native vector for nontemporal builtins

__device__ __forceinline__ unsigned hash_slot(unsigned key) {
    return (key * 2654435761u) >> 14;   // top 18 bits of Knuth hash -> [0, 2^18)
}

// ---------------- K0: init scratch ----------------
__global__ void k_init(int* hashKey, int* hashVal, int* rowcnt, float* S) {
    int i = blockIdx.x * blockDim.x + threadIdx.x;
    if (i < HASH_T) { hashKey[i] = -1; hashVal[i] = -1; }
    if (i < N_NODES) rowcnt[i] = 0;
    if (i < HC)      S[i] = 0.f;
}

// ---------------- K1: Wh = h @ W^T, s1/s2 per node/head, and column-sum S ----------------
// 8 nodes per block; thread t = head*64+o computes channel t for 8 nodes.
__global__ __launch_bounds__(256) void k_linear(
        const float* __restrict__ h, const float* __restrict__ W,
        const float* __restrict__ a,
        float* __restrict__ Wh, float* __restrict__ s1, float* __restrict__ s2,
        float* __restrict__ S) {
    __shared__ float hs[8][IN_F];
    const int t = threadIdx.x;
    const int node0 = blockIdx.x * 8;
    for (int n = 0; n < 8; ++n) hs[n][t] = h[(size_t)(node0 + n) * IN_F + t];
    __syncthreads();

    float acc[8] = {0.f, 0.f, 0.f, 0.f, 0.f, 0.f, 0.f, 0.f};
    const float4* wrow4 = (const float4*)(W + (size_t)t * IN_F);
    for (int j = 0; j < IN_F / 4; ++j) {
        float4 wv = wrow4[j];
#pragma unroll
        for (int n = 0; n < 8; ++n) {
            float4 hv = *(const float4*)&hs[n][j * 4];   // ds_read_b128 broadcast
            acc[n] = fmaf(wv.x, hv.x, acc[n]);
            acc[n] = fmaf(wv.y, hv.y, acc[n]);
            acc[n] = fmaf(wv.z, hv.z, acc[n]);
            acc[n] = fmaf(wv.w, hv.w, acc[n]);
        }
    }

    const int head = t >> 6, lane = t & 63;
    const float a1 = a[head * 2 * OUT_F + lane];
    const float a2 = a[head * 2 * OUT_F + OUT_F + lane];
    float colpart = 0.f;
    for (int n = 0; n < 8; ++n) {
        Wh[(size_t)(node0 + n) * HC + t] = acc[n];
        colpart += acc[n];
        float p1 = acc[n] * a1;
        float p2 = acc[n] * a2;
#pragma unroll
        for (int o = 32; o > 0; o >>= 1) {
            p1 += __shfl_xor(p1, o, 64);
            p2 += __shfl_xor(p2, o, 64);
        }
        if (lane == 0) {
            s1[(node0 + n) * HEADS + head] = p1;
            s2[(node0 + n) * HEADS + head] = p2;
        }
    }
    atomicAdd(&S[t], colpart);     // 512 adds per channel, fused column-sum
}

// ---------------- K2: hash insert (dedupe, last-k-wins) ----------------
__global__ void k_hash_insert(const int* __restrict__ rows, const int* __restrict__ cols,
                              int* hashKey, int* hashVal) {
    int k = blockIdx.x * blockDim.x + threadIdx.x;
    if (k >= E_EDGES) return;
    const int key = (rows[k] << 12) | cols[k];
    unsigned slot = hash_slot((unsigned)key);
    while (true) {
        int old = atomicCAS(&hashKey[slot], -1, key);
        if (old == -1 || old == key) { atomicMax(&hashVal[slot], k); break; }
        slot = (slot + 1) & HASH_MASK;
    }
}

// ---------------- K3: per-edge e values, winner flag, row counts ----------------
__global__ void k_edge(const int* __restrict__ rows, const int* __restrict__ cols,
                       const float* __restrict__ s1, const float* __restrict__ s2,
                       const int* __restrict__ hashKey, const int* __restrict__ hashVal,
                       float* __restrict__ e_vals, int* __restrict__ winner,
                       int* __restrict__ rowcnt) {
    int k = blockIdx.x * blockDim.x + threadIdx.x;
    if (k >= E_EDGES) return;
    const int r = rows[k], c = cols[k];
    float4 ev;
    {
        float x;
        x = s1[r * HEADS + 0] + s2[c * HEADS + 0]; ev.x = (x > 0.f) ? x : 0.2f * x;
        x = s1[r * HEADS + 1] + s2[c * HEADS + 1]; ev.y = (x > 0.f) ? x : 0.2f * x;
        x = s1[r * HEADS + 2] + s2[c * HEADS + 2]; ev.z = (x > 0.f) ? x : 0.2f * x;
        x = s1[r * HEADS + 3] + s2[c * HEADS + 3]; ev.w = (x > 0.f) ? x : 0.2f * x;
    }
    ((float4*)e_vals)[k] = ev;
    const int key = (r << 12) | c;
    unsigned slot = hash_slot((unsigned)key);
    while (hashKey[slot] != key) slot = (slot + 1) & HASH_MASK;
    const int win = (hashVal[slot] == k) ? 1 : 0;
    winner[k] = win;
    if (win) atomicAdd(&rowcnt[r], 1);
}

// ---------------- K4: exclusive scan of rowcnt -> rowptr, cursor ----------------
__global__ __launch_bounds__(1024) void k_scan(const int* __restrict__ rowcnt,
                                               int* rowptr, int* cursor) {
    __shared__ int part[1024];
    const int t = threadIdx.x;
    const int base = t * 4;
    int c0 = rowcnt[base], c1 = rowcnt[base + 1], c2 = rowcnt[base + 2], c3 = rowcnt[base + 3];
    int s = c0 + c1 + c2 + c3;
    part[t] = s;
    __syncthreads();
    for (int off = 1; off < 1024; off <<= 1) {
        int v = (t >= off) ? part[t - off] : 0;
        __syncthreads();
        part[t] += v;
        __syncthreads();
    }
    int excl = part[t] - s;
    rowptr[base]     = excl;
    rowptr[base + 1] = excl + c0;
    rowptr[base + 2] = excl + c0 + c1;
    rowptr[base + 3] = excl + c0 + c1 + c2;
    cursor[base]     = rowptr[base];
    cursor[base + 1] = rowptr[base + 1];
    cursor[base + 2] = rowptr[base + 2];
    cursor[base + 3] = rowptr[base + 3];
    if (t == 1023) rowptr[N_NODES] = part[1023];
}

// ---------------- K5: CSR fill with winner edge ids ----------------
__global__ void k_csr_fill(const int* __restrict__ rows, const int* __restrict__ winner,
                           int* cursor, int* edgelist) {
    int k = blockIdx.x * blockDim.x + threadIdx.x;
    if (k >= E_EDGES) return;
    if (winner[k]) {
        int pos = atomicAdd(&cursor[rows[k]], 1);
        edgelist[pos] = k;
    }
}

// ---------------- K6: per-row mega kernel: stats + attn row + out0 ----------------
__global__ __launch_bounds__(256) void k_row_mega(
        const int* __restrict__ rowptr, const int* __restrict__ edgelist,
        const int* __restrict__ cols, const float* __restrict__ e_vals,
        const float* __restrict__ S, const float* __restrict__ Wh,
        float* __restrict__ out0, float* __restrict__ attn) {
    __shared__ float rowbuf[N_NODES];          // 16 KB dense attn row
    __shared__ float whead[ECAP][HEADS];       // 8 KB per-edge per-head weights
    __shared__ int   ccache[ECAP];             // 2 KB per-edge cols
    __shared__ float mh[HEADS], dh[HEADS], bh[HEADS];

    const int i = blockIdx.x;
    const int t = threadIdx.x, head = t >> 6, lane = t & 63;
    const int start = rowptr[i], end = rowptr[i + 1], cnt = end - start;

    // pass 1: per-head max over this row's edges (one wave per head)
    float emax = -1e30f;
    for (int p = start + lane; p < end; p += 64)
        emax = fmaxf(emax, e_vals[(size_t)edgelist[p] * HEADS + head]);
#pragma unroll
    for (int o = 32; o > 0; o >>= 1) emax = fmaxf(emax, __shfl_xor(emax, o, 64));
    const float m = fmaxf(emax, 0.f);   // dense row always has zero background cells

    // pass 2: per-head exp-sum
    float ssum = 0.f;
    for (int p = start + lane; p < end; p += 64)
        ssum += __expf(e_vals[(size_t)edgelist[p] * HEADS + head] - m);
#pragma unroll
    for (int o = 32; o > 0; o >>= 1) ssum += __shfl_xor(ssum, o, 64);

    if (lane == 0) {
        const float denom = ssum + (float)(N_NODES - cnt) * __expf(-m);
        mh[head] = m;
        dh[head] = denom;
        bh[head] = __expf(-m) / denom;
    }
    __syncthreads();
    const float bsum = 0.25f * (bh[0] + bh[1] + bh[2] + bh[3]);

    // fill LDS row with background
    {
        float4 v4 = make_float4(bsum, bsum, bsum, bsum);
        float4* rb4 = (float4*)rowbuf;
        for (int j = t; j < N_NODES / 4; j += 256) rb4[j] = v4;
    }
    __syncthreads();

    // scatter edge alphas into LDS row; cache per-head weights + cols
    for (int p = start + t; p < end; p += 256) {
        const int k = edgelist[p];
        const int c = cols[k];
        const float4 ev = ((const float4*)e_vals)[k];
        float w0 = __expf(ev.x - mh[0]) / dh[0];
        float w1 = __expf(ev.y - mh[1]) / dh[1];
        float w2 = __expf(ev.z - mh[2]) / dh[2];
        float w3 = __expf(ev.w - mh[3]) / dh[3];
        rowbuf[c] = 0.25f * (w0 + w1 + w2 + w3);
        const int q = p - start;
        if (q < ECAP) {
            whead[q][0] = w0; whead[q][1] = w1; whead[q][2] = w2; whead[q][3] = w3;
            ccache[q] = c;
        }
    }
    __syncthreads();

    // stream attn row to global, nontemporal (never re-read; don't pollute L2)
    {
        const v4f* src = (const v4f*)rowbuf;
        v4f* dst = (v4f*)(attn + (size_t)i * N_NODES);
        for (int j = t; j < N_NODES / 4; j += 256)
            __builtin_nontemporal_store(src[j], &dst[j]);
    }

    // out0: thread t owns channel t
    const float m_ = mh[head], d_ = dh[head], b_ = bh[head];
    float acc = b_ * S[t];
    for (int q = 0; q < cnt; ++q) {
        float w; int c;
        if (q < ECAP) { w = whead[q][head]; c = ccache[q]; }
        else {
            const int k = edgelist[start + q];
            c = cols[k];
            w = __expf(e_vals[(size_t)k * HEADS + head] - m_) / d_;
        }
        acc += (w - b_) * Wh[(size_t)c * HC + t];
    }
    out0[(size_t)i * HC + t] = fmaxf(acc, 0.f);
}

extern "C" void kernel_launch(void* const* d_in, const int* in_sizes, int n_in,
                              void* d_out, int out_size, void* d_ws, size_t ws_size,
                              hipStream_t stream) {
    const float* h  = (const float*)d_in[0];
    const int*   ei = (const int*)d_in[1];
    const float* W  = (const float*)d_in[2];
    const float* a  = (const float*)d_in[3];
    const int* rows = ei;
    const int* cols = ei + E_EDGES;

    float* out0 = (float*)d_out;
    float* attn = out0 + (size_t)N_NODES * HC;

    // workspace carve (all offsets 256B aligned)
    char* p = (char*)d_ws;
    auto carve = [&](size_t bytes) { char* q = p; p += (bytes + 255) & ~(size_t)255; return q; };
    float* Wh      = (float*)carve(sizeof(float) * (size_t)N_NODES * HC);
    float* s1      = (float*)carve(sizeof(float) * N_NODES * HEADS);
    float* s2      = (float*)carve(sizeof(float) * N_NODES * HEADS);
    float* S       = (float*)carve(sizeof(float) * HC);
    float* e_vals  = (float*)carve(sizeof(float) * (size_t)E_EDGES * HEADS);
    int* hashKey   = (int*)carve(sizeof(int) * HASH_T);
    int* hashVal   = (int*)carve(sizeof(int) * HASH_T);
    int* winner    = (int*)carve(sizeof(int) * E_EDGES);
    int* rowcnt    = (int*)carve(sizeof(int) * N_NODES);
    int* rowptr    = (int*)carve(sizeof(int) * (N_NODES + 4));
    int* cursor    = (int*)carve(sizeof(int) * N_NODES);
    int* edgelist  = (int*)carve(sizeof(int) * E_EDGES);

    k_init<<<(HASH_T + 255) / 256, 256, 0, stream>>>(hashKey, hashVal, rowcnt, S);
    k_linear<<<N_NODES / 8, 256, 0, stream>>>(h, W, a, Wh, s1, s2, S);
    k_hash_insert<<<E_EDGES / 256, 256, 0, stream>>>(rows, cols, hashKey, hashVal);
    k_edge<<<E_EDGES / 256, 256, 0, stream>>>(rows, cols, s1, s2, hashKey, hashVal,
                                              e_vals, winner, rowcnt);
    k_scan<<<1, 1024, 0, stream>>>(rowcnt, rowptr, cursor);
    k_csr_fill<<<E_EDGES / 256, 256, 0, stream>>>(rows, winner, cursor, edgelist);
    k_row_mega<<<N_NODES, 256, 0, stream>>>(rowptr, edgelist, cols, e_vals, S, Wh,
                                            out0, attn);
}